// Round 4
// baseline (120.864 us; speedup 1.0000x reference)
//
#include <hip/hip_runtime.h>
#include <hip/hip_bf16.h>

#define B_   4
#define N_   2048
#define C_   1024
#define NT   32
#define QSCALE 0.18033688011112042f   // 0.125 * log2(e)

typedef __attribute__((ext_vector_type(8)))  short short8;
typedef __attribute__((ext_vector_type(4)))  float f32x4;
typedef __attribute__((ext_vector_type(16))) float f32x16;
typedef __attribute__((ext_vector_type(2)))  int   int2v;

__device__ __forceinline__ unsigned short f2bf(float x) {
    union { __hip_bfloat16 h; unsigned short u; } c;
    c.h = __float2bfloat16(x);
    return c.u;
}
__device__ __forceinline__ float fast_exp2(float x) {
    float r; asm("v_exp_f32 %0, %1" : "=v"(r) : "v"(x)); return r;
}
__device__ __forceinline__ int cvtpk(float a, float b) {
    int r; asm("v_cvt_pk_bf16_f32 %0, %1, %2" : "=v"(r) : "v"(a), "v"(b)); return r;
}

// ---- pre-pass: f32 [B,N,C] -> bf16 tiles in MFMA-FRAGMENT order ----
// Per (head,tile): K frag cell c (c = f*64+lane, f = ks*2+kvh):
//   row = (f&1)*32 + (lane&31), col = (f>>1)*16 + (lane>>5)*8 .. +8
//   stored at tile_base + c*8 elems  -> wave fragment load = contiguous 1KB.
// V^T same formula on [d][kv].
__global__ __launch_bounds__(256) void prepack(
    const float* __restrict__ K, const float* __restrict__ V,
    unsigned short* __restrict__ Kt, unsigned short* __restrict__ Vt)
{
    __shared__ __align__(16) unsigned short kl[4096];
    __shared__ __align__(16) unsigned short vl[4096];
    const int L = blockIdx.x;              // 2048
    const int xcd = L & 7;
    const int j = L >> 3;                  // 0..255
    const int head = xcd + 8 * (j >> 5);   // same head->XCD map as attn
    const int t = j & 31;
    const int b = head >> 4, h = head & 15;
    const int tid = threadIdx.x;
    const int r = tid >> 2, cb = tid & 3;
    const size_t head_off = (size_t)b * N_ * C_ + (size_t)h * 64;
    const int kv0 = t * 64;
    const int blk_out = head * NT + t;

    // K tile: coalesced read -> bf16 -> LDS [kv][d] (swizzled)
    {
        const float* src = K + head_off + (size_t)(kv0 + r) * C_ + cb * 16;
        f32x4 x0 = *(const f32x4*)(src);
        f32x4 x1 = *(const f32x4*)(src + 4);
        f32x4 x2 = *(const f32x4*)(src + 8);
        f32x4 x3 = *(const f32x4*)(src + 12);
        short8 p0, p1;
        #pragma unroll
        for (int i = 0; i < 4; ++i) {
            p0[i] = (short)f2bf(x0[i]); p0[i + 4] = (short)f2bf(x1[i]);
            p1[i] = (short)f2bf(x2[i]); p1[i + 4] = (short)f2bf(x3[i]);
        }
        const int swz = (r & 7) << 3;
        *(short8*)&kl[r * 64 + ((cb * 16) ^ swz)]     = p0;
        *(short8*)&kl[r * 64 + ((cb * 16 + 8) ^ swz)] = p1;
    }
    // V tile: coalesced read -> transpose into LDS [d][kv] (swizzled)
    {
        const float* src = V + head_off + (size_t)(kv0 + r) * C_ + cb * 16;
        f32x4 y0 = *(const f32x4*)(src);
        f32x4 y1 = *(const f32x4*)(src + 4);
        f32x4 y2 = *(const f32x4*)(src + 8);
        f32x4 y3 = *(const f32x4*)(src + 12);
        #pragma unroll
        for (int i = 0; i < 4; ++i) {
            int d0 = cb * 16 + i;
            vl[d0 * 64 + (r ^ ((d0 & 7) << 3))] = f2bf(y0[i]);
            int d1 = cb * 16 + 4 + i;
            vl[d1 * 64 + (r ^ ((d1 & 7) << 3))] = f2bf(y1[i]);
            int d2 = cb * 16 + 8 + i;
            vl[d2 * 64 + (r ^ ((d2 & 7) << 3))] = f2bf(y2[i]);
            int d3 = cb * 16 + 12 + i;
            vl[d3 * 64 + (r ^ ((d3 & 7) << 3))] = f2bf(y3[i]);
        }
    }
    __syncthreads();
    // write out in fragment order (coalesced 16B stores)
    #pragma unroll
    for (int cc = 0; cc < 2; ++cc) {
        const int c  = tid + cc * 256;
        const int f  = c >> 6;
        const int ln = c & 63;
        const int row = (f & 1) * 32 + (ln & 31);
        const int col = (f >> 1) * 16 + (ln >> 5) * 8;
        const int sw  = (row & 7) << 3;
        short8 kk = *(const short8*)&kl[row * 64 + (col ^ sw)];
        short8 vv = *(const short8*)&vl[row * 64 + (col ^ sw)];
        *(short8*)&Kt[(size_t)blk_out * 4096 + c * 8] = kk;
        *(short8*)&Vt[(size_t)blk_out * 4096 + c * 8] = vv;
    }
}

// ---- main attention: no LDS, no barriers; fragments straight from L1/L2 ----
__global__ __launch_bounds__(256, 4) void attn_fwd(
    const float* __restrict__ Q, const unsigned short* __restrict__ Kt,
    const unsigned short* __restrict__ Vt, float* __restrict__ O)
{
    const int L = blockIdx.x;              // 1024 blocks
    const int xcd = L & 7;
    const int j = L >> 3;                  // 0..127
    const int head = xcd + 8 * (j >> 4);   // all 16 q-blocks of a head on one XCD
    const int qt = j & 15;
    const int b = head >> 4, h = head & 15;

    const int tid  = threadIdx.x;
    const int wave = tid >> 6;
    const int lane = tid & 63;
    const int l31  = lane & 31;
    const int hi   = lane >> 5;

    const unsigned short* kbase = Kt + (size_t)head * (NT * 4096);
    const unsigned short* vbase = Vt + (size_t)head * (NT * 4096);
    const float* qp = Q + (size_t)b * N_ * C_ + (size_t)h * 64;
    float*       op = O + (size_t)b * N_ * C_ + (size_t)h * 64;

    // Q B-fragments: col q = qt*128 + wave*32 + l31, k = ks*16 + hi*8 + j
    const int qrow = qt * 128 + wave * 32 + l31;
    short8 qfrag[4];
    {
        const float* qr = qp + (size_t)qrow * C_ + hi * 8;
        #pragma unroll
        for (int ks = 0; ks < 4; ++ks) {
            f32x4 x0 = *(const f32x4*)(qr + ks * 16);
            f32x4 x1 = *(const f32x4*)(qr + ks * 16 + 4);
            short8 a;
            #pragma unroll
            for (int i = 0; i < 4; ++i) {
                a[i]     = (short)f2bf(x0[i] * QSCALE);
                a[i + 4] = (short)f2bf(x1[i] * QSCALE);
            }
            qfrag[ks] = a;
        }
    }

    f32x16 o0 = {}, o1 = {};
    float m_r = -3.0e38f, l_r = 0.0f;

    const int lofs = lane * 8;

    for (int t = 0; t < NT; ++t) {
        const unsigned short* ktp = kbase + (size_t)t * 4096;
        const unsigned short* vtp = vbase + (size_t)t * 4096;

        // --- QK^T swapped: S^T[kv][q]; lane: q = l31 ---
        f32x16 s0 = {}, s1 = {};
        __builtin_amdgcn_s_setprio(1);
        #pragma unroll
        for (int ks = 0; ks < 4; ++ks) {
            short8 kf0 = *(const short8*)(ktp + ks * 1024 + lofs);
            short8 kf1 = *(const short8*)(ktp + ks * 1024 + 512 + lofs);
            s0 = __builtin_amdgcn_mfma_f32_32x32x16_bf16(kf0, qfrag[ks], s0, 0, 0, 0);
            s1 = __builtin_amdgcn_mfma_f32_32x32x16_bf16(kf1, qfrag[ks], s1, 0, 0, 0);
        }
        __builtin_amdgcn_s_setprio(0);

        // --- in-lane max over 32 scores + cross-half permlane swap ---
        float mx[8];
        #pragma unroll
        for (int r = 0; r < 8; ++r) mx[r] = fmaxf(fmaxf(s0[r], s0[r + 8]), fmaxf(s1[r], s1[r + 8]));
        #pragma unroll
        for (int st = 4; st; st >>= 1) {
            #pragma unroll
            for (int r = 0; r < st; ++r) mx[r] = fmaxf(mx[r], mx[r + st]);
        }
        int2v msw = __builtin_amdgcn_permlane32_swap(__float_as_int(mx[0]), __float_as_int(mx[0]), false, false);
        const float rm = fmaxf(__int_as_float(msw[0]), __int_as_float(msw[1]));

        if (!__all(rm - m_r <= 8.0f)) {      // T13 defer-max
            const float mnew = fmaxf(m_r, rm);
            const float corr = fast_exp2(m_r - mnew);
            m_r = mnew;
            l_r *= corr;
            #pragma unroll
            for (int r = 0; r < 16; ++r) { o0[r] *= corr; o1[r] *= corr; }
        }

        // --- P = exp2(S - m) ---
        #pragma unroll
        for (int r = 0; r < 16; ++r) {
            s0[r] = fast_exp2(s0[r] - m_r);
            s1[r] = fast_exp2(s1[r] - m_r);
        }
        // row sum
        float aa[8];
        #pragma unroll
        for (int r = 0; r < 8; ++r) aa[r] = (s0[r] + s0[r + 8]) + (s1[r] + s1[r + 8]);
        #pragma unroll
        for (int st = 4; st; st >>= 1) {
            #pragma unroll
            for (int r = 0; r < st; ++r) aa[r] += aa[r + st];
        }
        int2v ssw = __builtin_amdgcn_permlane32_swap(__float_as_int(aa[0]), __float_as_int(aa[0]), false, false);
        l_r += __int_as_float(ssw[0]) + __int_as_float(ssw[1]);

        // --- T12: P -> bf16 PV B-fragments via cvt_pk + permlane32_swap ---
        short8 pf[4];
        #pragma unroll
        for (int ct = 0; ct < 2; ++ct) {
            #pragma unroll
            for (int kss = 0; kss < 2; ++kss) {
                float e0, e1, e2, e3, e4, e5, e6, e7;
                if (ct == 0) {
                    e0 = s0[8*kss+0]; e1 = s0[8*kss+1]; e2 = s0[8*kss+2]; e3 = s0[8*kss+3];
                    e4 = s0[8*kss+4]; e5 = s0[8*kss+5]; e6 = s0[8*kss+6]; e7 = s0[8*kss+7];
                } else {
                    e0 = s1[8*kss+0]; e1 = s1[8*kss+1]; e2 = s1[8*kss+2]; e3 = s1[8*kss+3];
                    e4 = s1[8*kss+4]; e5 = s1[8*kss+5]; e6 = s1[8*kss+6]; e7 = s1[8*kss+7];
                }
                int w0 = cvtpk(e0, e1);
                int w1 = cvtpk(e2, e3);
                int w2 = cvtpk(e4, e5);
                int w3 = cvtpk(e6, e7);
                int2v sA = __builtin_amdgcn_permlane32_swap(w0, w2, false, false);
                int2v sB = __builtin_amdgcn_permlane32_swap(w1, w3, false, false);
                union { int i[4]; short8 v; } u;
                u.i[0] = sA[0]; u.i[1] = sB[0]; u.i[2] = sA[1]; u.i[3] = sB[1];
                pf[ct * 2 + kss] = u.v;
            }
        }

        // --- PV swapped: O^T[d][q] += V^T[d][kv] * P^T[kv][q] ---
        __builtin_amdgcn_s_setprio(1);
        #pragma unroll
        for (int ks = 0; ks < 4; ++ks) {
            short8 vf0 = *(const short8*)(vtp + ks * 1024 + lofs);
            short8 vf1 = *(const short8*)(vtp + ks * 1024 + 512 + lofs);
            o0 = __builtin_amdgcn_mfma_f32_32x32x16_bf16(vf0, pf[ks], o0, 0, 0, 0);
            o1 = __builtin_amdgcn_mfma_f32_32x32x16_bf16(vf1, pf[ks], o1, 0, 0, 0);
        }
        __builtin_amdgcn_s_setprio(0);
    }

    // --- epilogue: per-lane normalize, lane owns q row; d = (r&3) + 8*(r>>2) + 4*hi ---
    const float inv = 1.0f / l_r;
    float* orow = op + (size_t)qrow * C_;
    #pragma unroll
    for (int bb = 0; bb < 4; ++bb) {
        f32x4 w0, w1;
        #pragma unroll
        for (int i = 0; i < 4; ++i) {
            w0[i] = o0[4 * bb + i] * inv;
            w1[i] = o1[4 * bb + i] * inv;
        }
        *(f32x4*)(orow + 8 * bb + 4 * hi)      = w0;
        *(f32x4*)(orow + 32 + 8 * bb + 4 * hi) = w1;
    }
}

extern "C" void kernel_launch(void* const* d_in, const int* in_sizes, int n_in,
                              void* d_out, int out_size, void* d_ws, size_t ws_size,
                              hipStream_t stream) {
    const float* q = (const float*)d_in[0];
    const float* k = (const float*)d_in[1];
    const float* v = (const float*)d_in[2];
    float* o = (float*)d_out;
    unsigned short* Kt = (unsigned short*)d_ws;                 // 16 MB
    unsigned short* Vt = Kt + (size_t)64 * NT * 4096;           // +16 MB
    prepack<<<dim3(64 * NT), dim3(256), 0, stream>>>(k, v, Kt, Vt);
    attn_fwd<<<dim3(1024), dim3(256), 0, stream>>>(q, Kt, Vt, o);
}

// Round 5
// 111.489 us; speedup vs baseline: 1.0841x; 1.0841x over previous
//
#include <hip/hip_runtime.h>
#include <hip/hip_bf16.h>

#define B_   4
#define N_   2048
#define C_   1024
#define NT   32
#define QSCALE 0.18033688011112042f   // 0.125 * log2(e)

typedef __attribute__((ext_vector_type(8)))  short short8;
typedef __attribute__((ext_vector_type(4)))  float f32x4;
typedef __attribute__((ext_vector_type(16))) float f32x16;
typedef __attribute__((ext_vector_type(2)))  int   int2v;

__device__ __forceinline__ unsigned short f2bf(float x) {
    union { __hip_bfloat16 h; unsigned short u; } c;
    c.h = __float2bfloat16(x);
    return c.u;
}
__device__ __forceinline__ float fast_exp2(float x) {
    float r; asm("v_exp_f32 %0, %1" : "=v"(r) : "v"(x)); return r;
}
__device__ __forceinline__ int cvtpk(float a, float b) {
    int r; asm("v_cvt_pk_bf16_f32 %0, %1, %2" : "=v"(r) : "v"(a), "v"(b)); return r;
}

// ---- pre-pass: f32 [B,N,C] -> bf16 tiles in MFMA-FRAGMENT order ----
// Per (head,tile) 8KB image, fragment f (0..7), cell c = f*64 + lane:
//   row = (f&1)*32 + (lane&31), col = (f>>1)*16 + (lane>>5)*8 .. +8
//   at elem offset c*8  -> a fragment load is 64 lanes x 16B contiguous.
__global__ __launch_bounds__(256) void prepack(
    const float* __restrict__ K, const float* __restrict__ V,
    unsigned short* __restrict__ Kt, unsigned short* __restrict__ Vt)
{
    __shared__ __align__(16) unsigned short kl[4096];
    __shared__ __align__(16) unsigned short vl[4096];
    const int L = blockIdx.x;              // 2048
    const int xcd = L & 7;
    const int j = L >> 3;                  // 0..255
    const int head = xcd + 8 * (j >> 5);   // same head->XCD map as attn
    const int t = j & 31;
    const int b = head >> 4, h = head & 15;
    const int tid = threadIdx.x;
    const int r = tid >> 2, cb = tid & 3;
    const size_t head_off = (size_t)b * N_ * C_ + (size_t)h * 64;
    const int kv0 = t * 64;
    const int blk_out = head * NT + t;

    // K tile: coalesced read -> bf16 -> LDS [kv][d] (swizzled)
    {
        const float* src = K + head_off + (size_t)(kv0 + r) * C_ + cb * 16;
        f32x4 x0 = *(const f32x4*)(src);
        f32x4 x1 = *(const f32x4*)(src + 4);
        f32x4 x2 = *(const f32x4*)(src + 8);
        f32x4 x3 = *(const f32x4*)(src + 12);
        short8 p0, p1;
        #pragma unroll
        for (int i = 0; i < 4; ++i) {
            p0[i] = (short)f2bf(x0[i]); p0[i + 4] = (short)f2bf(x1[i]);
            p1[i] = (short)f2bf(x2[i]); p1[i + 4] = (short)f2bf(x3[i]);
        }
        const int swz = (r & 7) << 3;
        *(short8*)&kl[r * 64 + ((cb * 16) ^ swz)]     = p0;
        *(short8*)&kl[r * 64 + ((cb * 16 + 8) ^ swz)] = p1;
    }
    // V tile: coalesced read -> transpose into LDS [d][kv] (swizzled)
    {
        const float* src = V + head_off + (size_t)(kv0 + r) * C_ + cb * 16;
        f32x4 y0 = *(const f32x4*)(src);
        f32x4 y1 = *(const f32x4*)(src + 4);
        f32x4 y2 = *(const f32x4*)(src + 8);
        f32x4 y3 = *(const f32x4*)(src + 12);
        #pragma unroll
        for (int i = 0; i < 4; ++i) {
            int d0 = cb * 16 + i;
            vl[d0 * 64 + (r ^ ((d0 & 7) << 3))] = f2bf(y0[i]);
            int d1 = cb * 16 + 4 + i;
            vl[d1 * 64 + (r ^ ((d1 & 7) << 3))] = f2bf(y1[i]);
            int d2 = cb * 16 + 8 + i;
            vl[d2 * 64 + (r ^ ((d2 & 7) << 3))] = f2bf(y2[i]);
            int d3 = cb * 16 + 12 + i;
            vl[d3 * 64 + (r ^ ((d3 & 7) << 3))] = f2bf(y3[i]);
        }
    }
    __syncthreads();
    // write out in fragment order (coalesced 16B stores)
    #pragma unroll
    for (int cc = 0; cc < 2; ++cc) {
        const int c  = tid + cc * 256;
        const int f  = c >> 6;
        const int ln = c & 63;
        const int row = (f & 1) * 32 + (ln & 31);
        const int col = (f >> 1) * 16 + (ln >> 5) * 8;
        const int sw  = (row & 7) << 3;
        short8 kk = *(const short8*)&kl[row * 64 + (col ^ sw)];
        short8 vv = *(const short8*)&vl[row * 64 + (col ^ sw)];
        *(short8*)&Kt[(size_t)blk_out * 4096 + c * 8] = kk;
        *(short8*)&Vt[(size_t)blk_out * 4096 + c * 8] = vv;
    }
}

// ---- main attention: LDS dbuf staging of fragment-ordered tiles ----
__global__ __launch_bounds__(256, 4) void attn_fwd(
    const float* __restrict__ Q, const unsigned short* __restrict__ Kt,
    const unsigned short* __restrict__ Vt, float* __restrict__ O)
{
    __shared__ __align__(16) unsigned short klds[2][4096];
    __shared__ __align__(16) unsigned short vlds[2][4096];

    const int L = blockIdx.x;              // 1024 blocks
    const int xcd = L & 7;
    const int j = L >> 3;                  // 0..127
    const int head = xcd + 8 * (j >> 4);   // all 16 q-blocks of a head on one XCD
    const int qt = j & 15;
    const int b = head >> 4, h = head & 15;

    const int tid  = threadIdx.x;
    const int wave = tid >> 6;
    const int lane = tid & 63;
    const int l31  = lane & 31;
    const int hi   = lane >> 5;

    const unsigned short* kbase = Kt + (size_t)head * (NT * 4096);
    const unsigned short* vbase = Vt + (size_t)head * (NT * 4096);
    const float* qp = Q + (size_t)b * N_ * C_ + (size_t)h * 64;
    float*       op = O + (size_t)b * N_ * C_ + (size_t)h * 64;

    // Q B-fragments: col q = qt*128 + wave*32 + l31, k = ks*16 + hi*8 + j
    const int qrow = qt * 128 + wave * 32 + l31;
    short8 qfrag[4];
    {
        const float* qr = qp + (size_t)qrow * C_ + hi * 8;
        #pragma unroll
        for (int ks = 0; ks < 4; ++ks) {
            f32x4 x0 = *(const f32x4*)(qr + ks * 16);
            f32x4 x1 = *(const f32x4*)(qr + ks * 16 + 4);
            short8 a;
            #pragma unroll
            for (int i = 0; i < 4; ++i) {
                a[i]     = (short)f2bf(x0[i] * QSCALE);
                a[i + 4] = (short)f2bf(x1[i] * QSCALE);
            }
            qfrag[ks] = a;
        }
    }

    f32x16 o0 = {}, o1 = {};
    float m_r = -3.0e38f, l_r = 0.0f;

    const int lofs = lane * 8;             // elem offset within a 512-elem fragment

    auto stage = [&](int t, int buf) {
        // linear copy: fragment order == lane order; each wave moves 2KB of K + 2KB of V
        const unsigned short* kg = kbase + (size_t)t * 4096 + wave * 1024 + lofs;
        const unsigned short* vg = vbase + (size_t)t * 4096 + wave * 1024 + lofs;
        __builtin_amdgcn_global_load_lds((const __attribute__((address_space(1))) void*)kg,
            (__attribute__((address_space(3))) void*)&klds[buf][wave * 1024], 16, 0, 0);
        __builtin_amdgcn_global_load_lds((const __attribute__((address_space(1))) void*)(kg + 512),
            (__attribute__((address_space(3))) void*)&klds[buf][wave * 1024 + 512], 16, 0, 0);
        __builtin_amdgcn_global_load_lds((const __attribute__((address_space(1))) void*)vg,
            (__attribute__((address_space(3))) void*)&vlds[buf][wave * 1024], 16, 0, 0);
        __builtin_amdgcn_global_load_lds((const __attribute__((address_space(1))) void*)(vg + 512),
            (__attribute__((address_space(3))) void*)&vlds[buf][wave * 1024 + 512], 16, 0, 0);
    };

    stage(0, 0);
    int cur = 0;

    for (int t = 0; t < NT; ++t) {
        asm volatile("s_waitcnt vmcnt(0)" ::: "memory");
        __syncthreads();
        if (t + 1 < NT) stage(t + 1, cur ^ 1);   // prefetch hides under compute below

        const unsigned short* kl = klds[cur];
        const unsigned short* vl = vlds[cur];

        // --- QK^T swapped: S^T[kv][q]; lane: q = l31 ---
        f32x16 s0 = {}, s1 = {};
        __builtin_amdgcn_s_setprio(1);
        #pragma unroll
        for (int ks = 0; ks < 4; ++ks) {
            short8 kf0 = *(const short8*)&kl[ks * 1024 + lofs];         // frag f=2ks
            short8 kf1 = *(const short8*)&kl[ks * 1024 + 512 + lofs];   // frag f=2ks+1
            s0 = __builtin_amdgcn_mfma_f32_32x32x16_bf16(kf0, qfrag[ks], s0, 0, 0, 0);
            s1 = __builtin_amdgcn_mfma_f32_32x32x16_bf16(kf1, qfrag[ks], s1, 0, 0, 0);
        }
        __builtin_amdgcn_s_setprio(0);

        // --- in-lane max over 32 scores + cross-half permlane swap ---
        float mx[8];
        #pragma unroll
        for (int r = 0; r < 8; ++r) mx[r] = fmaxf(fmaxf(s0[r], s0[r + 8]), fmaxf(s1[r], s1[r + 8]));
        #pragma unroll
        for (int st = 4; st; st >>= 1) {
            #pragma unroll
            for (int r = 0; r < st; ++r) mx[r] = fmaxf(mx[r], mx[r + st]);
        }
        int2v msw = __builtin_amdgcn_permlane32_swap(__float_as_int(mx[0]), __float_as_int(mx[0]), false, false);
        const float rm = fmaxf(__int_as_float(msw[0]), __int_as_float(msw[1]));

        if (!__all(rm - m_r <= 8.0f)) {      // T13 defer-max
            const float mnew = fmaxf(m_r, rm);
            const float corr = fast_exp2(m_r - mnew);
            m_r = mnew;
            l_r *= corr;
            #pragma unroll
            for (int r = 0; r < 16; ++r) { o0[r] *= corr; o1[r] *= corr; }
        }

        // --- P = exp2(S - m) ---
        #pragma unroll
        for (int r = 0; r < 16; ++r) {
            s0[r] = fast_exp2(s0[r] - m_r);
            s1[r] = fast_exp2(s1[r] - m_r);
        }
        // row sum
        float aa[8];
        #pragma unroll
        for (int r = 0; r < 8; ++r) aa[r] = (s0[r] + s0[r + 8]) + (s1[r] + s1[r + 8]);
        #pragma unroll
        for (int st = 4; st; st >>= 1) {
            #pragma unroll
            for (int r = 0; r < st; ++r) aa[r] += aa[r + st];
        }
        int2v ssw = __builtin_amdgcn_permlane32_swap(__float_as_int(aa[0]), __float_as_int(aa[0]), false, false);
        l_r += __int_as_float(ssw[0]) + __int_as_float(ssw[1]);

        // --- T12: P -> bf16 PV B-fragments via cvt_pk + permlane32_swap ---
        short8 pf[4];
        #pragma unroll
        for (int ct = 0; ct < 2; ++ct) {
            #pragma unroll
            for (int kss = 0; kss < 2; ++kss) {
                float e0, e1, e2, e3, e4, e5, e6, e7;
                if (ct == 0) {
                    e0 = s0[8*kss+0]; e1 = s0[8*kss+1]; e2 = s0[8*kss+2]; e3 = s0[8*kss+3];
                    e4 = s0[8*kss+4]; e5 = s0[8*kss+5]; e6 = s0[8*kss+6]; e7 = s0[8*kss+7];
                } else {
                    e0 = s1[8*kss+0]; e1 = s1[8*kss+1]; e2 = s1[8*kss+2]; e3 = s1[8*kss+3];
                    e4 = s1[8*kss+4]; e5 = s1[8*kss+5]; e6 = s1[8*kss+6]; e7 = s1[8*kss+7];
                }
                int w0 = cvtpk(e0, e1);
                int w1 = cvtpk(e2, e3);
                int w2 = cvtpk(e4, e5);
                int w3 = cvtpk(e6, e7);
                int2v sA = __builtin_amdgcn_permlane32_swap(w0, w2, false, false);
                int2v sB = __builtin_amdgcn_permlane32_swap(w1, w3, false, false);
                union { int i[4]; short8 v; } u;
                u.i[0] = sA[0]; u.i[1] = sB[0]; u.i[2] = sA[1]; u.i[3] = sB[1];
                pf[ct * 2 + kss] = u.v;
            }
        }

        // --- PV swapped: O^T[d][q] += V^T[d][kv] * P^T[kv][q] ---
        __builtin_amdgcn_s_setprio(1);
        #pragma unroll
        for (int ks = 0; ks < 4; ++ks) {
            short8 vf0 = *(const short8*)&vl[ks * 1024 + lofs];
            short8 vf1 = *(const short8*)&vl[ks * 1024 + 512 + lofs];
            o0 = __builtin_amdgcn_mfma_f32_32x32x16_bf16(vf0, pf[ks], o0, 0, 0, 0);
            o1 = __builtin_amdgcn_mfma_f32_32x32x16_bf16(vf1, pf[ks], o1, 0, 0, 0);
        }
        __builtin_amdgcn_s_setprio(0);

        cur ^= 1;
    }

    // --- epilogue: per-lane normalize; lane owns q row; d = 8*bb + 4*hi + i (+32 for o1) ---
    const float inv = 1.0f / l_r;
    float* orow = op + (size_t)qrow * C_;
    #pragma unroll
    for (int bb = 0; bb < 4; ++bb) {
        f32x4 w0, w1;
        #pragma unroll
        for (int i = 0; i < 4; ++i) {
            w0[i] = o0[4 * bb + i] * inv;
            w1[i] = o1[4 * bb + i] * inv;
        }
        *(f32x4*)(orow + 8 * bb + 4 * hi)      = w0;
        *(f32x4*)(orow + 32 + 8 * bb + 4 * hi) = w1;
    }
}

extern "C" void kernel_launch(void* const* d_in, const int* in_sizes, int n_in,
                              void* d_out, int out_size, void* d_ws, size_t ws_size,
                              hipStream_t stream) {
    const float* q = (const float*)d_in[0];
    const float* k = (const float*)d_in[1];
    const float* v = (const float*)d_in[2];
    float* o = (float*)d_out;
    unsigned short* Kt = (unsigned short*)d_ws;                 // 16 MB
    unsigned short* Vt = Kt + (size_t)64 * NT * 4096;           // +16 MB
    prepack<<<dim3(64 * NT), dim3(256), 0, stream>>>(k, v, Kt, Vt);
    attn_fwd<<<dim3(1024), dim3(256), 0, stream>>>(q, Kt, Vt, o);
}